// Round 2
// baseline (3767.149 us; speedup 1.0000x reference)
//
#include <hip/hip_runtime.h>

// Problem constants (fixed by setup_inputs)
#define BB 32
#define NN 64
#define TT 11
#define FF 4
#define KK 2
#define EE 4032      // N*(N-1)
#define NSTEP 10

typedef _Float16 f16x8 __attribute__((ext_vector_type(8)));
typedef float    f32x4v __attribute__((ext_vector_type(4)));

// ---- stage kernel LDS: u[k][64][512B swz] 64K | vb[k][8][256]f16 8K | wgt[k][8][64]f32 4K | agg[8][256]f32 8K
#define OFF_U    0
#define OFF_VB   65536
#define OFF_WGT  73728
#define OFF_AGG  77824
#define SMEM2    86016

__device__ __forceinline__ float scrub(float v) {
    return fminf(fmaxf(v, -3.0e4f), 3.0e4f);   // inactive when correct (|x| <~ 600)
}

__device__ __forceinline__ float load_dt(const float* ts, const void* scp, int step) {
    float t0 = ts[step], t1 = ts[step + 1];
    int w = ((const int*)scp)[0];
    float scl;
    if (w > 0 && w < 1000000) scl = (float)w;            // int32 (live path)
    else {
        float f = __int_as_float(w);
        scl = (f > 0.5f && f < 1.0e6f) ? f : 10.0f;
    }
    return (t1 - t0) / scl;
}

typedef __attribute__((address_space(1))) const unsigned int glb_u32;
typedef __attribute__((address_space(3))) unsigned int lds_u32;
__device__ __forceinline__ void gload_lds16(const void* g, void* l) {
    __builtin_amdgcn_global_load_lds((glb_u32*)g, (lds_u32*)l, 16, 0, 0);
}

// ---- shared u/vb emission: u[b][k][n][256] f16 (row-XOR-swizzled bytes), vb linear ----
// u swizzle: within (b,k) slab, element (n,h) lives at byte n*512 + ((2h) ^ ((n&7)<<4)).
__device__ __forceinline__ void emit_uvb(int tid, int row0,
    const float (*smYn)[4],
    const float* __restrict__ w1p, const float* __restrict__ b1p,
    _Float16* __restrict__ uG, _Float16* __restrict__ vbG)
{
    const int hc = tid & 31, kk = (tid >> 5) & 1, rr = tid >> 6;
    const int h0 = hc * 8;
    const int row = row0 + rr;
    const int bb = row >> 6, n = row & 63;
    const float* wp = w1p + kk * 2048 + h0;
    f32x4v ul = {0.f, 0.f, 0.f, 0.f}, uh = {0.f, 0.f, 0.f, 0.f};
    f32x4v vl = *(const f32x4v*)(b1p + kk * 256 + h0);
    f32x4v vh = *(const f32x4v*)(b1p + kk * 256 + h0 + 4);
    #pragma unroll
    for (int f = 0; f < 4; ++f) {
        const float y = smYn[rr][f];
        const f32x4v yv = {y, y, y, y};
        ul += yv * *(const f32x4v*)(wp + f * 256);
        uh += yv * *(const f32x4v*)(wp + f * 256 + 4);
        vl += yv * *(const f32x4v*)(wp + (4 + f) * 256);
        vh += yv * *(const f32x4v*)(wp + (4 + f) * 256 + 4);
    }
    f16x8 uu8, vv8;
    #pragma unroll
    for (int e = 0; e < 4; ++e) {
        uu8[e] = (_Float16)ul[e]; uu8[e + 4] = (_Float16)uh[e];
        vv8[e] = (_Float16)vl[e]; vv8[e + 4] = (_Float16)vh[e];
    }
    const size_t slab = ((size_t)bb * 2 + kk) * 16384;           // elements per (b,k)
    char* up = (char*)uG + slab * 2 + n * 512 + ((h0 * 2) ^ ((n & 7) << 4));
    *(f16x8*)up = uu8;
    *(f16x8*)(vbG + slab + (size_t)n * 256 + h0) = vv8;
}

// Edge-GEMM + aggregation for one RK4 stage.
// v3: block = (b, 8 receivers), 512 threads, grid 256 = 1 block/CU.
//   - u (both k, 64 KiB) staged ONCE per 8 receivers (u L2 traffic 64->16 MiB/dispatch)
//   - wave tile = 2 concurrent receivers x 64 cols (ni=4): each bfr B-fragment feeds
//     8 MFMAs (was 4) -> W2F L2 stream halved (512->256 MiB/dispatch)
//   - coalesced agg write via LDS (kills 33 MB partial-line RMW)
// Regs: acc[2][4][4]=128 (AGPR) + bfr 16 + af 32 + misc -> 2 waves/SIMD.
__global__ __launch_bounds__(512, 2)
void stage_kernel(const float* __restrict__ edges, const _Float16* __restrict__ W2F,
                  const float* __restrict__ b2g,
                  const _Float16* __restrict__ uG, const _Float16* __restrict__ vbG,
                  float* __restrict__ aggg)
{
    extern __shared__ char smem[];
    float* smWgt = (float*)(smem + OFF_WGT);
    float* smAgg = (float*)(smem + OFF_AGG);

    const int tid  = threadIdx.x;
    const int b    = blockIdx.x >> 3;
    const int rg8  = blockIdx.x & 7;
    const int r0   = rg8 * 8;
    const int lane = tid & 63;
    const int wn   = tid >> 6;          // 0..7

    // ---- staging: u (64 KiB, both k) + vb (8 KiB) direct to LDS, wgt scalar ----
    {
        const char* uGb = (const char*)(uG + (size_t)b * 2 * 16384);
        #pragma unroll
        for (int c = 0; c < 8; ++c) {
            int cc = wn + c * 8;        // 64 chunks of 1 KiB
            gload_lds16(uGb + cc * 1024 + lane * 16, smem + OFF_U + cc * 1024);
        }
        int kk = wn >> 2, q = wn & 3;   // vb rows r0..r0+7, per k 4 KiB
        const char* vGb = (const char*)(vbG + ((size_t)b * 2 + kk) * 16384 + (size_t)r0 * 256);
        gload_lds16(vGb + q * 1024 + lane * 16, smem + OFF_VB + wn * 1024);
    }
    #pragma unroll
    for (int it = 0; it < 2; ++it) {
        int i = tid + it * 512;         // [k][rl][jj]
        int k = i >> 9, m = i & 511;
        int rl = m >> 6, jj = m & 63;
        float w = 0.0f;
        if (jj < 63) w = edges[((size_t)b * EE + (r0 + rl) * 63 + jj) * KK + k];
        smWgt[i] = w;
    }

    const int rp   = wn >> 2;           // receiver-pair group (0/1)
    const int cq   = wn & 3;            // col quarter (0..3)
    const int ln15 = lane & 15;
    const int lg   = lane >> 4;         // 0..3

    __syncthreads();   // drains vmcnt (global_load_lds) + LDS stores

    float rsA[2][2][4];                 // [tp][u][ni]
    #pragma unroll
    for (int tp = 0; tp < 2; ++tp)
        #pragma unroll
        for (int uu = 0; uu < 2; ++uu)
            #pragma unroll
            for (int ni = 0; ni < 4; ++ni) rsA[tp][uu][ni] = 0.0f;

    #pragma unroll 1
    for (int tp = 0; tp < 2; ++tp) {
        // receivers for this pass: r = r0 + rp*4 + tp*2 + uu
        int uoff[2][4], xmh[2][4];
        #pragma unroll
        for (int uu = 0; uu < 2; ++uu) {
            int r = r0 + rp * 4 + tp * 2 + uu;
            #pragma unroll
            for (int mi = 0; mi < 4; ++mi) {
                int jj = mi * 16 + ln15;
                int s = jj + (jj >= r ? 1 : 0);
                if (s > 63) s = 63;     // jj==63 is the pad slot (wgt=0)
                int xm = (s & 7) << 4;
                uoff[uu][mi] = s * 512 + ((lg * 16) ^ (xm & 48));
                xmh[uu][mi]  = xm & 64;
            }
        }
        const int rv0 = rp * 4 + tp * 2;    // block-local receiver index of uu=0

        #pragma unroll 1
        for (int k = 0; k < 2; ++k) {
            const _Float16* bbase = W2F + ((size_t)((k * 16 + cq * 4) * 8)) * 512 + lane * 8;
            const char* ubase = smem + OFF_U + k * 32768;
            const char* vbase = smem + OFF_VB + (k * 8 + rv0) * 512;

            float bv[4];
            #pragma unroll
            for (int ni = 0; ni < 4; ++ni)
                bv[ni] = b2g[k * 256 + cq * 64 + ni * 16 + ln15];

            f32x4v acc[2][4][4];            // b2 folded into init
            #pragma unroll
            for (int uu = 0; uu < 2; ++uu)
                #pragma unroll
                for (int mi = 0; mi < 4; ++mi)
                    #pragma unroll
                    for (int ni = 0; ni < 4; ++ni)
                        acc[uu][mi][ni] = (f32x4v){bv[ni], bv[ni], bv[ni], bv[ni]};

            #pragma unroll
            for (int kc = 0; kc < 8; ++kc) {
                f16x8 bfr[4];
                #pragma unroll
                for (int ni = 0; ni < 4; ++ni)
                    bfr[ni] = *(const f16x8*)(bbase + (size_t)(ni * 8 + kc) * 512);
                f16x8 vb0 = *(const f16x8*)(vbase + kc * 64 + lg * 16);
                f16x8 vb1 = *(const f16x8*)(vbase + 512 + kc * 64 + lg * 16);
                f16x8 af[2][4]; f16x8 z = {};
                #pragma unroll
                for (int uu = 0; uu < 2; ++uu)
                    #pragma unroll
                    for (int mi = 0; mi < 4; ++mi) {
                        f16x8 uv = *(const f16x8*)(ubase + uoff[uu][mi] + ((kc * 64) ^ xmh[uu][mi]));
                        af[uu][mi] = __builtin_elementwise_max(uv + (uu ? vb1 : vb0), z);
                    }
                #pragma unroll
                for (int uu = 0; uu < 2; ++uu)
                    #pragma unroll
                    for (int mi = 0; mi < 4; ++mi)
                        #pragma unroll
                        for (int ni = 0; ni < 4; ++ni)
                            acc[uu][mi][ni] = __builtin_amdgcn_mfma_f32_16x16x32_f16(
                                af[uu][mi], bfr[ni], acc[uu][mi][ni], 0, 0, 0);
            }

            // ---- epilogue (per k): relu * edge_w, accumulate ----
            #pragma unroll
            for (int uu = 0; uu < 2; ++uu)
                #pragma unroll
                for (int mi = 0; mi < 4; ++mi)
                    #pragma unroll
                    for (int rr = 0; rr < 4; ++rr) {
                        // C/D: col = lane&15, row = (lane>>4)*4 + rr  [m89/m91]
                        float w = smWgt[k * 512 + (rv0 + uu) * 64 + mi * 16 + lg * 4 + rr];
                        #pragma unroll
                        for (int ni = 0; ni < 4; ++ni)
                            rsA[tp][uu][ni] += fmaxf(acc[uu][mi][ni][rr], 0.0f) * w;
                    }
        }
    }

    // ---- cross-lane reduce + LDS transpose + coalesced agg write ----
    #pragma unroll
    for (int tp = 0; tp < 2; ++tp)
        #pragma unroll
        for (int uu = 0; uu < 2; ++uu)
            #pragma unroll
            for (int ni = 0; ni < 4; ++ni) {
                float v = rsA[tp][uu][ni];
                v += __shfl_xor(v, 16, 64);
                v += __shfl_xor(v, 32, 64);
                rsA[tp][uu][ni] = v;
            }
    if (lane < 16) {
        #pragma unroll
        for (int tp = 0; tp < 2; ++tp)
            #pragma unroll
            for (int uu = 0; uu < 2; ++uu)
                #pragma unroll
                for (int ni = 0; ni < 4; ++ni)
                    smAgg[(rp * 4 + tp * 2 + uu) * 256 + cq * 64 + ni * 16 + ln15] = rsA[tp][uu][ni];
    }
    __syncthreads();
    {
        const float* asrc = (const float*)(smem + OFF_AGG);
        float* adst = aggg + ((size_t)(b * NN + r0)) * 256;
        #pragma unroll
        for (int it = 0; it < 4; ++it)
            adst[tid + it * 512] = asrc[tid + it * 512];
    }
}

// Node MLP (f32-exact) + RK4 tail + u/vb emission for the NEXT stage.
// v3: W1/b1 staged to LDS at kernel top via global_load_lds (drains at first barrier,
// overlaps the MLP phases); emit reads LDS with f32x4.
__global__ __launch_bounds__(256, 4)
void mlp_kernel(int stage, int step,
    const float* __restrict__ Wo1, const float* __restrict__ bo1,
    const float* __restrict__ Wo2, const float* __restrict__ bo2,
    const float* __restrict__ Wo3, const float* __restrict__ bo3,
    const float* __restrict__ W1g, const float* __restrict__ b1g,
    const float* __restrict__ ts,  const void* __restrict__ scp,
    const float* __restrict__ xcur, const float* __restrict__ kprev,
    const float* __restrict__ aggg,
    float* __restrict__ kout,
    const float* __restrict__ k1b, const float* __restrict__ k2b,
    const float* __restrict__ k3b,
    float* __restrict__ xnext, float* __restrict__ outp,
    _Float16* __restrict__ uG, _Float16* __restrict__ vbG)
{
    __shared__ float smAug[4][264];    // 264 -> 16B-aligned rows
    __shared__ float smP1[4][256];
    __shared__ float smP2[4][256];
    __shared__ float smYn[4][4];
    __shared__ float smW1[4096];       // W1 (2 KiB x 8) staged via gload_lds
    __shared__ float smB1[512];

    const int tid  = threadIdx.x;
    const int row0 = blockIdx.x * 4;

    // ---- W1/b1 -> LDS (async; drained by first barrier) ----
    {
        const int wv = tid >> 6, l = tid & 63;
        #pragma unroll
        for (int rnd = 0; rnd < 4; ++rnd)
            gload_lds16((const char*)W1g + wv * 1024 + rnd * 4096 + l * 16,
                        (char*)smW1 + wv * 1024 + rnd * 4096);
        if (wv < 2)
            gload_lds16((const char*)b1g + wv * 1024 + l * 16,
                        (char*)smB1 + wv * 1024);
    }

    const float dt = load_dt(ts, scp, step);
    const float cc = (stage == 0) ? 0.0f : ((stage == 3) ? 1.0f : 0.5f);

    // ---- stage aug = [y(4) | agg(256)] per row ----
    for (int u = tid; u < 1040; u += 256) {
        int rr = u / 260, h = u - rr * 260;
        int row = row0 + rr;
        float v;
        if (h < 4) {
            int gi = row * 4 + h;
            v = xcur[gi];
            if (stage != 0) v += cc * dt * kprev[gi];
            v = scrub(v);
        } else {
            v = aggg[(size_t)row * 256 + (h - 4)];
        }
        smAug[rr][h] = v;
    }
    __syncthreads();

    // ---- L1: 260 -> 256, relu ----
    {
        int c = tid;
        float a[4];
        float b0 = bo1[c];
        #pragma unroll
        for (int rr = 0; rr < 4; ++rr) a[rr] = b0;
        #pragma unroll 1
        for (int hb = 0; hb < 256; hb += 8) {
            float w[8];
            #pragma unroll
            for (int j = 0; j < 8; ++j) w[j] = Wo1[(size_t)(hb + j) * 256 + c];
            f32x4v xlo[4], xhi[4];
            #pragma unroll
            for (int rr = 0; rr < 4; ++rr) {
                xlo[rr] = *(const f32x4v*)(&smAug[rr][hb]);
                xhi[rr] = *(const f32x4v*)(&smAug[rr][hb + 4]);
            }
            #pragma unroll
            for (int jj = 0; jj < 4; ++jj)
                #pragma unroll
                for (int rr = 0; rr < 4; ++rr) {
                    a[rr] += xlo[rr][jj] * w[jj];
                    a[rr] += xhi[rr][jj] * w[4 + jj];
                }
        }
        #pragma unroll
        for (int j = 0; j < 4; ++j) {          // tail h = 256..259
            float wv = Wo1[(size_t)(256 + j) * 256 + c];
            #pragma unroll
            for (int rr = 0; rr < 4; ++rr)
                a[rr] += smAug[rr][256 + j] * wv;
        }
        #pragma unroll
        for (int rr = 0; rr < 4; ++rr)
            smP1[rr][c] = fmaxf(a[rr], 0.0f);
    }
    __syncthreads();
    // ---- L2: 256 -> 256, relu ----
    {
        int c = tid;
        float a[4];
        float b0 = bo2[c];
        #pragma unroll
        for (int rr = 0; rr < 4; ++rr) a[rr] = b0;
        #pragma unroll 1
        for (int hb = 0; hb < 256; hb += 8) {
            float w[8];
            #pragma unroll
            for (int j = 0; j < 8; ++j) w[j] = Wo2[(size_t)(hb + j) * 256 + c];
            f32x4v xlo[4], xhi[4];
            #pragma unroll
            for (int rr = 0; rr < 4; ++rr) {
                xlo[rr] = *(const f32x4v*)(&smP1[rr][hb]);
                xhi[rr] = *(const f32x4v*)(&smP1[rr][hb + 4]);
            }
            #pragma unroll
            for (int jj = 0; jj < 4; ++jj)
                #pragma unroll
                for (int rr = 0; rr < 4; ++rr) {
                    a[rr] += xlo[rr][jj] * w[jj];
                    a[rr] += xhi[rr][jj] * w[4 + jj];
                }
        }
        #pragma unroll
        for (int rr = 0; rr < 4; ++rr)
            smP2[rr][c] = fmaxf(a[rr], 0.0f);
    }
    __syncthreads();
    // ---- L3 (256 -> 4) + residual + RK4 tail + y_next stash ----
    {
        int rr = tid >> 6, f = (tid >> 4) & 3, hs = tid & 15;
        float part = 0.0f;
        #pragma unroll
        for (int j = 0; j < 16; ++j) {
            int h = hs + j * 16;
            part += smP2[rr][h] * Wo3[h * 4 + f];
        }
        part += __shfl_xor(part, 8, 64);
        part += __shfl_xor(part, 4, 64);
        part += __shfl_xor(part, 2, 64);
        part += __shfl_xor(part, 1, 64);
        if (hs == 0) {
            int row = row0 + rr;
            int gi  = row * 4 + f;
            float y = xcur[gi];
            if (stage != 0) y += cc * dt * kprev[gi];
            y = scrub(y);
            float knew = scrub(y + bo3[f] + part);    // f(y) = y + p
            float yn;
            if (stage < 3) {
                kout[gi] = knew;
                float cn = (stage == 2) ? 1.0f : 0.5f;   // next stage's coefficient
                yn = scrub(xcur[gi] + cn * dt * knew);
            } else {
                float xn = scrub(xcur[gi] + (dt * (1.0f / 6.0f)) *
                           (k1b[gi] + 2.0f * k2b[gi] + 2.0f * k3b[gi] + knew));
                xnext[gi] = xn;
                // out layout (B, N, NSTEP, F): row = b*64+n
                outp[(size_t)row * NSTEP * FF + step * FF + f] = xn;
                yn = xn;                                 // next step stage 0: y = x
            }
            smYn[rr][f] = yn;
        }
    }
    __syncthreads();
    emit_uvb(tid, row0, smYn, smW1, smB1, uG, vbG);
}

// One-time u/vb init from x0 (step 0 stage 0).
__global__ __launch_bounds__(256)
void uvb_init(const float* __restrict__ xA,
              const float* __restrict__ W1g, const float* __restrict__ b1g,
              _Float16* __restrict__ uG, _Float16* __restrict__ vbG)
{
    __shared__ float smYn[4][4];
    const int tid  = threadIdx.x;
    const int row0 = blockIdx.x * 4;
    if (tid < 16) smYn[tid >> 2][tid & 3] = xA[row0 * 4 + tid];
    __syncthreads();
    emit_uvb(tid, row0, smYn, W1g, b1g, uG, vbG);
}

// Pre-swizzle W2 -> fragment-major W2F (verified round 7): chunk (k,ot,kc) is
// 1 KiB; lane l holds B[o = ot*16 + (l&15)][h = kc*32 + (l>>4)*8 + e]
__global__ void swizzle_w2(const float* __restrict__ W2, _Float16* __restrict__ W2F)
{
    int idx = blockIdx.x * 256 + threadIdx.x;       // 0 .. 131071
    int k   = idx >> 16;
    int rem = idx & 65535;
    int ch  = rem >> 9;
    int pos = rem & 511;
    int ot  = ch >> 3, kc = ch & 7;
    int l   = pos >> 3, e = pos & 7;
    int o   = ot * 16 + (l & 15);
    int h   = kc * 32 + (l >> 4) * 8 + e;
    W2F[idx] = (_Float16)W2[(size_t)(k * 256 + h) * 256 + o];
}

__global__ void init_x(const float* __restrict__ inp, float* __restrict__ x0)
{
    int i = blockIdx.x * 256 + threadIdx.x;   // i = (b*64+n)*4+f
    if (i < BB * NN * FF) {
        int f = i & 3, bn = i >> 2;
        x0[i] = scrub(inp[(size_t)(bn * TT) * FF + f]);   // inputs[b][n][0][f]
    }
}

static int find_input(const int* in_sizes, int n_in, int want, unsigned char* used, int dflt) {
    if (dflt >= 0 && dflt < n_in && in_sizes[dflt] == want && !used[dflt]) { used[dflt] = 1; return dflt; }
    for (int i = 0; i < n_in; ++i)
        if (!used[i] && in_sizes[i] == want) { used[i] = 1; return i; }
    return dflt;
}

extern "C" void kernel_launch(void* const* d_in, const int* in_sizes, int n_in,
                              void* d_out, int out_size, void* d_ws, size_t ws_size,
                              hipStream_t stream)
{
    unsigned char used[64] = {0};
    int iInp = find_input(in_sizes, n_in, BB*NN*TT*FF, used, 0);
    int iEdg = find_input(in_sizes, n_in, BB*EE*KK,    used, 1);
    (void)find_input(in_sizes, n_in, EE*NN, used, 2);              // rel_rec (unused)
    (void)find_input(in_sizes, n_in, EE*NN, used, 3);              // rel_send (unused)
    int iW1  = find_input(in_sizes, n_in, KK*8*256,  used, 4);
    int ib1  = find_input(in_sizes, n_in, KK*256,    used, 5);
    int iW2  = find_input(in_sizes, n_in, KK*256*256,used, 6);
    int ib2  = find_input(in_sizes, n_in, KK*256,    used, 7);
    int iWo1 = find_input(in_sizes, n_in, 260*256,   used, 8);
    int ibo1 = find_input(in_sizes, n_in, 256,       used, 9);
    int iWo2 = find_input(in_sizes, n_in, 256*256,   used, 10);
    int ibo2 = find_input(in_sizes, n_in, 256,       used, 11);
    int iWo3 = find_input(in_sizes, n_in, 256*4,     used, 12);
    int ibo3 = find_input(in_sizes, n_in, 4,         used, 13);
    int iTs  = find_input(in_sizes, n_in, TT,        used, 14);
    (void)find_input(in_sizes, n_in, 1, used, 15);                 // pred_steps
    int iSc  = find_input(in_sizes, n_in, 1,         used, 16);    // scale

    const float* inputs = (const float*)d_in[iInp];
    const float* edges  = (const float*)d_in[iEdg];
    const float* W1  = (const float*)d_in[iW1];
    const float* b1  = (const float*)d_in[ib1];
    const float* W2  = (const float*)d_in[iW2];
    const float* b2  = (const float*)d_in[ib2];
    const float* Wo1 = (const float*)d_in[iWo1];
    const float* bo1 = (const float*)d_in[ibo1];
    const float* Wo2 = (const float*)d_in[iWo2];
    const float* bo2 = (const float*)d_in[ibo2];
    const float* Wo3 = (const float*)d_in[iWo3];
    const float* bo3 = (const float*)d_in[ibo3];
    const float* ts  = (const float*)d_in[iTs];
    const void*  scp = d_in[iSc];

    char* ws = (char*)d_ws;
    _Float16* W2F = (_Float16*)ws;                     // 262144 B
    float* xA  = (float*)(ws + 262144);
    float* xB  = (float*)(ws + 262144 + 1 * 32768);
    float* k1  = (float*)(ws + 262144 + 2 * 32768);
    float* k2  = (float*)(ws + 262144 + 3 * 32768);
    float* k3  = (float*)(ws + 262144 + 4 * 32768);
    float* agg = (float*)(ws + 262144 + 5 * 32768);    // 2048*256*4 = 2 MiB
    _Float16* uG  = (_Float16*)(ws + 262144 + 5 * 32768 + 2097152);            // 2 MiB
    _Float16* vbG = (_Float16*)(ws + 262144 + 5 * 32768 + 2097152 + 2097152);  // 2 MiB

    float* outp = (float*)d_out;   // f32 output

    (void)hipFuncSetAttribute((const void*)stage_kernel,
        hipFuncAttributeMaxDynamicSharedMemorySize, SMEM2);

    swizzle_w2<<<dim3(512), dim3(256), 0, stream>>>(W2, W2F);
    init_x<<<dim3(32), dim3(256), 0, stream>>>(inputs, xA);
    uvb_init<<<dim3(512), dim3(256), 0, stream>>>(xA, W1, b1, uG, vbG);

    float* xc = xA;
    float* xn = xB;
    for (int step = 0; step < NSTEP; ++step) {
        float* kprevs[4] = { xc, k1, k2, k3 };   // kprev per stage (xc unused at s0)
        float* kouts[4]  = { k1, k2, k3, k3 };   // kout per stage (s3 -> tail path)
        for (int s = 0; s < 4; ++s) {
            stage_kernel<<<dim3(256), dim3(512), SMEM2, stream>>>(
                edges, W2F, b2, uG, vbG, agg);
            mlp_kernel<<<dim3(512), dim3(256), 0, stream>>>(s, step,
                Wo1, bo1, Wo2, bo2, Wo3, bo3, W1, b1, ts, scp, xc, kprevs[s], agg,
                kouts[s], k1, k2, k3, xn, outp, uG, vbG);
        }
        float* t = xc; xc = xn; xn = t;
    }
}

// Round 3
// 2387.410 us; speedup vs baseline: 1.5779x; 1.5779x over previous
//
#include <hip/hip_runtime.h>

// Problem constants (fixed by setup_inputs)
#define BB 32
#define NN 64
#define TT 11
#define FF 4
#define KK 2
#define EE 4032      // N*(N-1)
#define NSTEP 10

typedef _Float16 f16x8 __attribute__((ext_vector_type(8)));
typedef float    f32x4v __attribute__((ext_vector_type(4)));

// ---- stage kernel LDS: u[64][512B XOR-swz] 32K | vbh[4][256]f16 2K | y[64][4]f32 1K | wgt[2][4][64]f32 2K
#define OFF_U    0
#define OFF_VB   32768
#define OFF_Y    34816
#define OFF_WGT  35840
#define SMEM2    37888

__device__ __forceinline__ float scrub(float v) {
    return fminf(fmaxf(v, -3.0e4f), 3.0e4f);   // inactive when correct (|x| <~ 600)
}

__device__ __forceinline__ float load_dt(const float* ts, const void* scp, int step) {
    float t0 = ts[step], t1 = ts[step + 1];
    int w = ((const int*)scp)[0];
    float scl;
    if (w > 0 && w < 1000000) scl = (float)w;            // int32 (live path)
    else {
        float f = __int_as_float(w);
        scl = (f > 0.5f && f < 1.0e6f) ? f : 10.0f;
    }
    return (t1 - t0) / scl;
}

// Edge-GEMM + aggregation for one RK4 stage.
// v4 (revert of the global-u experiment + surgical changes on the verified round-0 base):
//  - block = (batch, 4 receivers), 512 threads / 8 waves, grid 512. Same wave tile as
//    round 0 (128 rows x 64 cols, acc[8][4]) and same ~8 waves/CU occupancy, but
//    u-build redundancy halves (32x -> 16x) and staging/barriers amortize 2x better.
//  - sender-major rows: m = rl*64 + s (diagonal s==r gets wgt 0) -> no svec gather,
//    no pad-slot clamp, u-swizzle XOR mask per-lane constant (one XOR per kc).
//  - u stored XOR-swizzled (byte ^= (s&7)<<4 within 512B rows): 2-way max on gather.
//  - b2 folded into acc init.
__global__ __launch_bounds__(512, 2)
void stage_kernel(int stage, int step,
    const float* __restrict__ edges, const float* __restrict__ W1g,
    const float* __restrict__ b1g,   const _Float16* __restrict__ W2F,
    const float* __restrict__ b2g,   const float* __restrict__ ts,
    const void* __restrict__ scp,
    const float* __restrict__ xcur,  const float* __restrict__ kprev,
    float* __restrict__ aggg)
{
    extern __shared__ char smem[];
    _Float16* smVBH = (_Float16*)(smem + OFF_VB);
    float*  smY   = (float*)(smem + OFF_Y);
    float*  smWgt = (float*)(smem + OFF_WGT);

    const int tid = threadIdx.x;
    const int b   = blockIdx.x >> 4;
    const int rg  = blockIdx.x & 15;
    const int r0  = rg * 4;

    const float dt = load_dt(ts, scp, step);
    const float cc = (stage == 0) ? 0.0f : ((stage == 3) ? 1.0f : 0.5f);

    // ---- P0: y (all 64 nodes) by first 256 threads; edge weights sender-major ----
    if (tid < 256) {
        int gi = (b * NN) * FF + tid;           // tid = n*4+f
        float y = xcur[gi];
        if (stage != 0) y += cc * dt * kprev[gi];
        smY[tid] = scrub(y);
    }
    {
        // smWgt[(k*4+rv)*64 + s] ; diagonal s==r -> 0
        int k = tid >> 8, rv = (tid >> 6) & 3, s = tid & 63;
        int r = r0 + rv;
        float w = 0.0f;
        if (s != r) {
            int j = s - (s > r ? 1 : 0);
            w = edges[((size_t)b * EE + r * 63 + j) * KK + k];
        }
        smWgt[tid] = w;
    }

    const int lane = tid & 63;
    const int wn   = tid >> 6;    // 8 waves: (rp = wn>>2 receiver-pair, cq = wn&3 col-quarter)
    const int rp   = wn >> 2;
    const int cq   = wn & 3;
    const int ln15 = lane & 15;
    const int lg   = lane >> 4;   // 0..3

    // swizzled u read offsets: byte = s*512 + ((kc*64 + lg*16) ^ ((s&7)<<4)),
    // s = (mi&3)*16 + ln15 -> s&7 = ln15&7 (per-lane constant).
    // split into uoff[mi] (bits 4-5) + kco (bits >=6, one XOR per kc).
    const int xm45 = (ln15 & 3) << 4;
    const int xm6  = (ln15 & 4) << 4;
    int uoff[8];
    #pragma unroll
    for (int mi = 0; mi < 8; ++mi) {
        int s = (mi & 3) * 16 + ln15;
        uoff[mi] = s * 512 + ((lg * 16) ^ xm45);
    }

    float rsum[2][4];             // [rl][ni], accumulated across k
    #pragma unroll
    for (int rl = 0; rl < 2; ++rl)
        #pragma unroll
        for (int ni = 0; ni < 4; ++ni) rsum[rl][ni] = 0.0f;

    for (int k = 0; k < KK; ++k) {
        __syncthreads();          // P0 ready / prev-k readers of smU,smVBH done
        // ---- u-build (512 thr): u[s][h] = sum_f y_s[f] * W1send[k][f][h], f16, XOR-swz ----
        {
            int hg = tid & 31, sb = tid >> 5;          // sb = 0..15
            const float* w1p = W1g + k * 2048 + hg * 8;
            f32x4v wA[4], wB[4];
            #pragma unroll
            for (int f = 0; f < 4; ++f) {
                wA[f] = *(const f32x4v*)(w1p + f * 256);
                wB[f] = *(const f32x4v*)(w1p + f * 256 + 4);
            }
            const int swz = (hg * 16) ^ ((sb & 7) << 4);   // s&7 == sb&7 (it*16 = 0 mod 8... it*16&7==0)
            #pragma unroll
            for (int it = 0; it < 4; ++it) {
                int s = sb + it * 16;
                f32x4v yv = *(const f32x4v*)(smY + s * 4);
                f16x8 uv;
                #pragma unroll
                for (int e = 0; e < 4; ++e) {
                    float vA = yv[0]*wA[0][e] + yv[1]*wA[1][e] + yv[2]*wA[2][e] + yv[3]*wA[3][e];
                    float vB = yv[0]*wB[0][e] + yv[1]*wB[1][e] + yv[2]*wB[2][e] + yv[3]*wB[3][e];
                    uv[e]     = (_Float16)vA;
                    uv[e + 4] = (_Float16)vB;
                }
                *(f16x8*)(smem + OFF_U + s * 512 + swz) = uv;
            }
        }
        // ---- vbh[rv][h] = f16( b1 + sum_f y_recv[f] * W1recv[k][f][h] ), rv = 0..3 ----
        #pragma unroll
        for (int it = 0; it < 2; ++it) {
            int i = tid + it * 512;
            int rv = i >> 8, h = i & 255;
            float acch = b1g[k * 256 + h];
            #pragma unroll
            for (int f = 0; f < 4; ++f)
                acch += smY[(r0 + rv) * 4 + f] * W1g[k * 2048 + (4 + f) * 256 + h];
            smVBH[i] = (_Float16)acch;
        }
        __syncthreads();          // u + vbh ready

        // ---- GEMM: kc-outer, af[8] cached, 4 ni-MFMAs per af ----
        float bv[4];
        #pragma unroll
        for (int ni = 0; ni < 4; ++ni)
            bv[ni] = b2g[k * 256 + cq * 64 + ni * 16 + ln15];

        f32x4v acc[8][4];         // b2 folded into init
        #pragma unroll
        for (int mi = 0; mi < 8; ++mi)
            #pragma unroll
            for (int ni = 0; ni < 4; ++ni)
                acc[mi][ni] = (f32x4v){bv[ni], bv[ni], bv[ni], bv[ni]};

        const _Float16* bbase = W2F
            + ((size_t)((k * 16 + cq * 4) * 8)) * 512 + lane * 8;
        const char* ubase = smem + OFF_U;
        const char* vbase = (const char*)(smVBH + rp * 512);   // rows rp*2, rp*2+1

        #pragma unroll
        for (int kc = 0; kc < 8; ++kc) {
            f16x8 bfr[4];
            #pragma unroll
            for (int ni = 0; ni < 4; ++ni)
                bfr[ni] = *(const f16x8*)(bbase + (size_t)(ni * 8 + kc) * 512);
            f16x8 vbA = *(const f16x8*)(vbase + (kc * 32 + lg * 8) * 2);
            f16x8 vbB = *(const f16x8*)(vbase + (256 + kc * 32 + lg * 8) * 2);
            const int kco = (kc * 64) ^ xm6;
            f16x8 af[8];
            f16x8 z = {};
            #pragma unroll
            for (int mi = 0; mi < 8; ++mi) {
                f16x8 uv = *(const f16x8*)(ubase + uoff[mi] + kco);
                af[mi] = __builtin_elementwise_max(uv + (mi < 4 ? vbA : vbB), z);
            }
            #pragma unroll
            for (int mi = 0; mi < 8; ++mi)
                #pragma unroll
                for (int ni = 0; ni < 4; ++ni)
                    acc[mi][ni] = __builtin_amdgcn_mfma_f32_16x16x32_f16(
                        af[mi], bfr[ni], acc[mi][ni], 0, 0, 0);
        }

        // ---- epilogue (per k): relu * edge_w, accumulate rsum ----
        #pragma unroll
        for (int mi = 0; mi < 8; ++mi) {
            int rl = mi >> 2;
            #pragma unroll
            for (int rr = 0; rr < 4; ++rr) {
                // C/D: col = lane&15, row = (lane>>4)*4 + rr  [m89/m91]; sender s = (mi&3)*16 + row
                float w = smWgt[(k * 4 + rp * 2 + rl) * 64 + (mi & 3) * 16 + lg * 4 + rr];
                #pragma unroll
                for (int ni = 0; ni < 4; ++ni)
                    rsum[rl][ni] += fmaxf(acc[mi][ni][rr], 0.0f) * w;
            }
        }
    }

    // ---- cross-lane reduce + direct global agg write (unique (row,o) writer) ----
    #pragma unroll
    for (int rl = 0; rl < 2; ++rl)
        #pragma unroll
        for (int ni = 0; ni < 4; ++ni) {
            rsum[rl][ni] += __shfl_xor(rsum[rl][ni], 16, 64);
            rsum[rl][ni] += __shfl_xor(rsum[rl][ni], 32, 64);
        }
    if (lane < 16) {
        #pragma unroll
        for (int rl = 0; rl < 2; ++rl)
            #pragma unroll
            for (int ni = 0; ni < 4; ++ni) {
                int o = cq * 64 + ni * 16 + ln15;
                aggg[(size_t)(b * NN + r0 + rp * 2 + rl) * 256 + o] = rsum[rl][ni];
            }
    }
}

// Node MLP (f32-exact) + RK4 tail. Block = 4 rows; 512 blocks. (round-0 verified version)
__global__ __launch_bounds__(256, 4)
void mlp_kernel(int stage, int step,
    const float* __restrict__ Wo1, const float* __restrict__ bo1,
    const float* __restrict__ Wo2, const float* __restrict__ bo2,
    const float* __restrict__ Wo3, const float* __restrict__ bo3,
    const float* __restrict__ ts,  const void* __restrict__ scp,
    const float* __restrict__ xcur, const float* __restrict__ kprev,
    const float* __restrict__ aggg,
    float* __restrict__ kout,
    const float* __restrict__ k1b, const float* __restrict__ k2b,
    const float* __restrict__ k3b,
    float* __restrict__ xnext, float* __restrict__ outp)
{
    __shared__ float smAug[4][264];    // 264 -> 16B-aligned rows
    __shared__ float smP1[4][256];
    __shared__ float smP2[4][256];

    const int tid  = threadIdx.x;
    const int row0 = blockIdx.x * 4;

    const float dt = load_dt(ts, scp, step);
    const float cc = (stage == 0) ? 0.0f : ((stage == 3) ? 1.0f : 0.5f);

    // ---- stage aug = [y(4) | agg(256)] per row ----
    for (int u = tid; u < 1040; u += 256) {
        int rr = u / 260, h = u - rr * 260;
        int row = row0 + rr;
        float v;
        if (h < 4) {
            int gi = row * 4 + h;
            v = xcur[gi];
            if (stage != 0) v += cc * dt * kprev[gi];
            v = scrub(v);
        } else {
            v = aggg[(size_t)row * 256 + (h - 4)];
        }
        smAug[rr][h] = v;
    }
    __syncthreads();

    // ---- L1: 260 -> 256, relu ----
    {
        int c = tid;
        float a[4];
        float b0 = bo1[c];
        #pragma unroll
        for (int rr = 0; rr < 4; ++rr) a[rr] = b0;
        #pragma unroll 1
        for (int hb = 0; hb < 256; hb += 8) {
            float w[8];
            #pragma unroll
            for (int j = 0; j < 8; ++j) w[j] = Wo1[(size_t)(hb + j) * 256 + c];
            f32x4v xlo[4], xhi[4];
            #pragma unroll
            for (int rr = 0; rr < 4; ++rr) {
                xlo[rr] = *(const f32x4v*)(&smAug[rr][hb]);
                xhi[rr] = *(const f32x4v*)(&smAug[rr][hb + 4]);
            }
            #pragma unroll
            for (int jj = 0; jj < 4; ++jj)
                #pragma unroll
                for (int rr = 0; rr < 4; ++rr) {
                    a[rr] += xlo[rr][jj] * w[jj];
                    a[rr] += xhi[rr][jj] * w[4 + jj];
                }
        }
        #pragma unroll
        for (int j = 0; j < 4; ++j) {          // tail h = 256..259
            float wv = Wo1[(size_t)(256 + j) * 256 + c];
            #pragma unroll
            for (int rr = 0; rr < 4; ++rr)
                a[rr] += smAug[rr][256 + j] * wv;
        }
        #pragma unroll
        for (int rr = 0; rr < 4; ++rr)
            smP1[rr][c] = fmaxf(a[rr], 0.0f);
    }
    __syncthreads();
    // ---- L2: 256 -> 256, relu ----
    {
        int c = tid;
        float a[4];
        float b0 = bo2[c];
        #pragma unroll
        for (int rr = 0; rr < 4; ++rr) a[rr] = b0;
        #pragma unroll 1
        for (int hb = 0; hb < 256; hb += 8) {
            float w[8];
            #pragma unroll
            for (int j = 0; j < 8; ++j) w[j] = Wo2[(size_t)(hb + j) * 256 + c];
            f32x4v xlo[4], xhi[4];
            #pragma unroll
            for (int rr = 0; rr < 4; ++rr) {
                xlo[rr] = *(const f32x4v*)(&smP1[rr][hb]);
                xhi[rr] = *(const f32x4v*)(&smP1[rr][hb + 4]);
            }
            #pragma unroll
            for (int jj = 0; jj < 4; ++jj)
                #pragma unroll
                for (int rr = 0; rr < 4; ++rr) {
                    a[rr] += xlo[rr][jj] * w[jj];
                    a[rr] += xhi[rr][jj] * w[4 + jj];
                }
        }
        #pragma unroll
        for (int rr = 0; rr < 4; ++rr)
            smP2[rr][c] = fmaxf(a[rr], 0.0f);
    }
    __syncthreads();
    // ---- L3 (256 -> 4) + residual + RK4 tail ----
    {
        int rr = tid >> 6, f = (tid >> 4) & 3, hs = tid & 15;
        float part = 0.0f;
        #pragma unroll
        for (int j = 0; j < 16; ++j) {
            int h = hs + j * 16;
            part += smP2[rr][h] * Wo3[h * 4 + f];
        }
        part += __shfl_xor(part, 8, 64);
        part += __shfl_xor(part, 4, 64);
        part += __shfl_xor(part, 2, 64);
        part += __shfl_xor(part, 1, 64);
        if (hs == 0) {
            int row = row0 + rr;
            int gi  = row * 4 + f;
            float y = xcur[gi];
            if (stage != 0) y += cc * dt * kprev[gi];
            y = scrub(y);
            float knew = scrub(y + bo3[f] + part);    // f(y) = y + p
            if (stage < 3) {
                kout[gi] = knew;
            } else {
                float xn = scrub(xcur[gi] + (dt * (1.0f / 6.0f)) *
                           (k1b[gi] + 2.0f * k2b[gi] + 2.0f * k3b[gi] + knew));
                xnext[gi] = xn;
                // out layout (B, N, NSTEP, F): row = b*64+n
                outp[(size_t)row * NSTEP * FF + step * FF + f] = xn;
            }
        }
    }
}

// Pre-swizzle W2 -> fragment-major W2F (verified): chunk (k,ot,kc) is
// 1 KiB; lane l holds B[o = ot*16 + (l&15)][h = kc*32 + (l>>4)*8 + e]
__global__ void swizzle_w2(const float* __restrict__ W2, _Float16* __restrict__ W2F)
{
    int idx = blockIdx.x * 256 + threadIdx.x;       // 0 .. 131071
    int k   = idx >> 16;
    int rem = idx & 65535;
    int ch  = rem >> 9;
    int pos = rem & 511;
    int ot  = ch >> 3, kc = ch & 7;
    int l   = pos >> 3, e = pos & 7;
    int o   = ot * 16 + (l & 15);
    int h   = kc * 32 + (l >> 4) * 8 + e;
    W2F[idx] = (_Float16)W2[(size_t)(k * 256 + h) * 256 + o];
}

__global__ void init_x(const float* __restrict__ inp, float* __restrict__ x0)
{
    int i = blockIdx.x * 256 + threadIdx.x;   // i = (b*64+n)*4+f
    if (i < BB * NN * FF) {
        int f = i & 3, bn = i >> 2;
        x0[i] = scrub(inp[(size_t)(bn * TT) * FF + f]);   // inputs[b][n][0][f]
    }
}

static int find_input(const int* in_sizes, int n_in, int want, unsigned char* used, int dflt) {
    if (dflt >= 0 && dflt < n_in && in_sizes[dflt] == want && !used[dflt]) { used[dflt] = 1; return dflt; }
    for (int i = 0; i < n_in; ++i)
        if (!used[i] && in_sizes[i] == want) { used[i] = 1; return i; }
    return dflt;
}

extern "C" void kernel_launch(void* const* d_in, const int* in_sizes, int n_in,
                              void* d_out, int out_size, void* d_ws, size_t ws_size,
                              hipStream_t stream)
{
    unsigned char used[64] = {0};
    int iInp = find_input(in_sizes, n_in, BB*NN*TT*FF, used, 0);
    int iEdg = find_input(in_sizes, n_in, BB*EE*KK,    used, 1);
    (void)find_input(in_sizes, n_in, EE*NN, used, 2);              // rel_rec (unused)
    (void)find_input(in_sizes, n_in, EE*NN, used, 3);              // rel_send (unused)
    int iW1  = find_input(in_sizes, n_in, KK*8*256,  used, 4);
    int ib1  = find_input(in_sizes, n_in, KK*256,    used, 5);
    int iW2  = find_input(in_sizes, n_in, KK*256*256,used, 6);
    int ib2  = find_input(in_sizes, n_in, KK*256,    used, 7);
    int iWo1 = find_input(in_sizes, n_in, 260*256,   used, 8);
    int ibo1 = find_input(in_sizes, n_in, 256,       used, 9);
    int iWo2 = find_input(in_sizes, n_in, 256*256,   used, 10);
    int ibo2 = find_input(in_sizes, n_in, 256,       used, 11);
    int iWo3 = find_input(in_sizes, n_in, 256*4,     used, 12);
    int ibo3 = find_input(in_sizes, n_in, 4,         used, 13);
    int iTs  = find_input(in_sizes, n_in, TT,        used, 14);
    (void)find_input(in_sizes, n_in, 1, used, 15);                 // pred_steps
    int iSc  = find_input(in_sizes, n_in, 1,         used, 16);    // scale

    const float* inputs = (const float*)d_in[iInp];
    const float* edges  = (const float*)d_in[iEdg];
    const float* W1  = (const float*)d_in[iW1];
    const float* b1  = (const float*)d_in[ib1];
    const float* W2  = (const float*)d_in[iW2];
    const float* b2  = (const float*)d_in[ib2];
    const float* Wo1 = (const float*)d_in[iWo1];
    const float* bo1 = (const float*)d_in[ibo1];
    const float* Wo2 = (const float*)d_in[iWo2];
    const float* bo2 = (const float*)d_in[ibo2];
    const float* Wo3 = (const float*)d_in[iWo3];
    const float* bo3 = (const float*)d_in[ibo3];
    const float* ts  = (const float*)d_in[iTs];
    const void*  scp = d_in[iSc];

    char* ws = (char*)d_ws;
    _Float16* W2F = (_Float16*)ws;                     // 262144 B
    float* xA  = (float*)(ws + 262144);
    float* xB  = (float*)(ws + 262144 + 1 * 32768);
    float* k1  = (float*)(ws + 262144 + 2 * 32768);
    float* k2  = (float*)(ws + 262144 + 3 * 32768);
    float* k3  = (float*)(ws + 262144 + 4 * 32768);
    float* agg = (float*)(ws + 262144 + 5 * 32768);    // 2048*256*4 = 2 MiB

    float* outp = (float*)d_out;   // f32 output

    (void)hipFuncSetAttribute((const void*)stage_kernel,
        hipFuncAttributeMaxDynamicSharedMemorySize, SMEM2);

    swizzle_w2<<<dim3(512), dim3(256), 0, stream>>>(W2, W2F);
    init_x<<<dim3(32), dim3(256), 0, stream>>>(inputs, xA);

    float* xc = xA;
    float* xn = xB;
    for (int step = 0; step < NSTEP; ++step) {
        float* kprevs[4] = { xc, k1, k2, k3 };   // kprev per stage (xc unused at s0)
        float* kouts[4]  = { k1, k2, k3, k3 };   // kout per stage (s3 -> tail path)
        for (int s = 0; s < 4; ++s) {
            stage_kernel<<<dim3(512), dim3(512), SMEM2, stream>>>(s, step,
                edges, W1, b1, W2F, b2, ts, scp, xc, kprevs[s], agg);
            mlp_kernel<<<dim3(512), dim3(256), 0, stream>>>(s, step,
                Wo1, bo1, Wo2, bo2, Wo3, bo3, ts, scp, xc, kprevs[s], agg,
                kouts[s], k1, k2, k3, xn, outp);
        }
        float* t = xc; xc = xn; xn = t;
    }
}

// Round 4
// 2387.029 us; speedup vs baseline: 1.5782x; 1.0002x over previous
//
#include <hip/hip_runtime.h>

// Problem constants (fixed by setup_inputs)
#define BB 32
#define NN 64
#define TT 11
#define FF 4
#define KK 2
#define EE 4032      // N*(N-1)
#define NSTEP 10

typedef _Float16 f16x8 __attribute__((ext_vector_type(8)));
typedef float    f32x4v __attribute__((ext_vector_type(4)));

// ---- stage kernel LDS (double-buffered u/vbh for k-pipelining):
// u[2][64][512B XOR-swz] 64K | vbh[2][4][256]f16 4K | y[64][4]f32 1K | wgt[2][4][64]f32 2K
#define OFF_U0   0
#define OFF_VB   65536
#define OFF_Y    69632
#define OFF_WGT  70656
#define SMEM2    72704

__device__ __forceinline__ float scrub(float v) {
    return fminf(fmaxf(v, -3.0e4f), 3.0e4f);   // inactive when correct (|x| <~ 600)
}

__device__ __forceinline__ float load_dt(const float* ts, const void* scp, int step) {
    float t0 = ts[step], t1 = ts[step + 1];
    int w = ((const int*)scp)[0];
    float scl;
    if (w > 0 && w < 1000000) scl = (float)w;            // int32 (live path)
    else {
        float f = __int_as_float(w);
        scl = (f > 0.5f && f < 1.0e6f) ? f : 10.0f;
    }
    return (t1 - t0) / scl;
}

// u-build (512 thr): u[s][h] = sum_f y_s[f] * W1send[k][f][h], f16, XOR-swizzled rows.
__device__ __forceinline__ void build_uk(char* smem, int buf, int k, int tid,
    const float* __restrict__ W1g, const float* smY)
{
    int hg = tid & 31, sb = tid >> 5;          // sb = 0..15
    const float* w1p = W1g + k * 2048 + hg * 8;
    f32x4v wA[4], wB[4];
    #pragma unroll
    for (int f = 0; f < 4; ++f) {
        wA[f] = *(const f32x4v*)(w1p + f * 256);
        wB[f] = *(const f32x4v*)(w1p + f * 256 + 4);
    }
    const int swz = (hg * 16) ^ ((sb & 7) << 4);   // s&7 == sb&7 (it*16 ≡ 0 mod 8)
    char* ub = smem + OFF_U0 + buf * 32768;
    #pragma unroll
    for (int it = 0; it < 4; ++it) {
        int s = sb + it * 16;
        f32x4v yv = *(const f32x4v*)(smY + s * 4);
        f16x8 uv;
        #pragma unroll
        for (int e = 0; e < 4; ++e) {
            float vA = yv[0]*wA[0][e] + yv[1]*wA[1][e] + yv[2]*wA[2][e] + yv[3]*wA[3][e];
            float vB = yv[0]*wB[0][e] + yv[1]*wB[1][e] + yv[2]*wB[2][e] + yv[3]*wB[3][e];
            uv[e]     = (_Float16)vA;
            uv[e + 4] = (_Float16)vB;
        }
        *(f16x8*)(ub + s * 512 + swz) = uv;
    }
}

// vbh[buf][rv][h] = f16( b1 + sum_f y_recv[f] * W1recv[k][f][h] ), rv = 0..3
__device__ __forceinline__ void build_vbh(_Float16* smVBH, int buf, int k, int tid, int r0,
    const float* __restrict__ W1g, const float* __restrict__ b1g, const float* smY)
{
    #pragma unroll
    for (int it = 0; it < 2; ++it) {
        int i = tid + it * 512;
        int rv = i >> 8, h = i & 255;
        float acch = b1g[k * 256 + h];
        #pragma unroll
        for (int f = 0; f < 4; ++f)
            acch += smY[(r0 + rv) * 4 + f] * W1g[k * 2048 + (4 + f) * 256 + h];
        smVBH[buf * 1024 + i] = (_Float16)acch;
    }
}

// GEMM + epilogue for one k (reads ubuf[buf], vbh[buf]); accumulates rsum.
__device__ __forceinline__ void gemm_k(const char* smem, int buf, int k,
    const _Float16* __restrict__ W2F, const float* __restrict__ b2g, const float* smWgt,
    int lane, int rp, int cq, int ln15, int lg, const int* uoff, int xm6,
    float rsum[2][4])
{
    const _Float16* smVBH = (const _Float16*)(smem + OFF_VB);

    float bv[4];
    #pragma unroll
    for (int ni = 0; ni < 4; ++ni)
        bv[ni] = b2g[k * 256 + cq * 64 + ni * 16 + ln15];

    f32x4v acc[8][4];         // b2 folded into init
    #pragma unroll
    for (int mi = 0; mi < 8; ++mi)
        #pragma unroll
        for (int ni = 0; ni < 4; ++ni)
            acc[mi][ni] = (f32x4v){bv[ni], bv[ni], bv[ni], bv[ni]};

    const _Float16* bbase = W2F
        + ((size_t)((k * 16 + cq * 4) * 8)) * 512 + lane * 8;
    const char* ubase = smem + OFF_U0 + buf * 32768;
    const char* vbase = (const char*)(smVBH + buf * 1024 + rp * 512);  // rows rp*2, rp*2+1

    #pragma unroll
    for (int kc = 0; kc < 8; ++kc) {
        f16x8 bfr[4];
        #pragma unroll
        for (int ni = 0; ni < 4; ++ni)
            bfr[ni] = *(const f16x8*)(bbase + (size_t)(ni * 8 + kc) * 512);
        f16x8 vbA = *(const f16x8*)(vbase + (kc * 32 + lg * 8) * 2);
        f16x8 vbB = *(const f16x8*)(vbase + (256 + kc * 32 + lg * 8) * 2);
        const int kco = (kc * 64) ^ xm6;
        f16x8 af[8];
        f16x8 z = {};
        #pragma unroll
        for (int mi = 0; mi < 8; ++mi) {
            f16x8 uv = *(const f16x8*)(ubase + uoff[mi] + kco);
            af[mi] = __builtin_elementwise_max(uv + (mi < 4 ? vbA : vbB), z);
        }
        #pragma unroll
        for (int mi = 0; mi < 8; ++mi)
            #pragma unroll
            for (int ni = 0; ni < 4; ++ni)
                acc[mi][ni] = __builtin_amdgcn_mfma_f32_16x16x32_f16(
                    af[mi], bfr[ni], acc[mi][ni], 0, 0, 0);
    }

    // ---- epilogue (per k): relu * edge_w, accumulate rsum ----
    #pragma unroll
    for (int mi = 0; mi < 8; ++mi) {
        int rl = mi >> 2;
        #pragma unroll
        for (int rr = 0; rr < 4; ++rr) {
            // C/D: col = lane&15, row = (lane>>4)*4 + rr  [m89/m91]; sender s = (mi&3)*16 + row
            float w = smWgt[(k * 4 + rp * 2 + rl) * 64 + (mi & 3) * 16 + lg * 4 + rr];
            #pragma unroll
            for (int ni = 0; ni < 4; ++ni)
                rsum[rl][ni] += fmaxf(acc[mi][ni][rr], 0.0f) * w;
        }
    }
}

// Edge-GEMM + aggregation for one RK4 stage.
// v5: k-phase software pipeline on the verified v4 base. u/vbh double-buffered in LDS;
// build(k=1) is issued BEFORE GEMM(k=0) so its VALU interleaves with GEMM0's MFMAs
// (1 block/CU, 2 waves/SIMD from the same block -> phase serialization was the gap:
// MfmaUtil 28.6 + VALUBusy 36.5, neither saturated). Barriers: 4 -> 3.
__global__ __launch_bounds__(512, 2)
void stage_kernel(int stage, int step,
    const float* __restrict__ edges, const float* __restrict__ W1g,
    const float* __restrict__ b1g,   const _Float16* __restrict__ W2F,
    const float* __restrict__ b2g,   const float* __restrict__ ts,
    const void* __restrict__ scp,
    const float* __restrict__ xcur,  const float* __restrict__ kprev,
    float* __restrict__ aggg)
{
    extern __shared__ char smem[];
    _Float16* smVBH = (_Float16*)(smem + OFF_VB);
    float*  smY   = (float*)(smem + OFF_Y);
    float*  smWgt = (float*)(smem + OFF_WGT);

    const int tid = threadIdx.x;
    const int b   = blockIdx.x >> 4;
    const int rg  = blockIdx.x & 15;
    const int r0  = rg * 4;

    const float dt = load_dt(ts, scp, step);
    const float cc = (stage == 0) ? 0.0f : ((stage == 3) ? 1.0f : 0.5f);

    // ---- P0: y (all 64 nodes) by first 256 threads; edge weights sender-major ----
    if (tid < 256) {
        int gi = (b * NN) * FF + tid;           // tid = n*4+f
        float y = xcur[gi];
        if (stage != 0) y += cc * dt * kprev[gi];
        smY[tid] = scrub(y);
    }
    {
        // smWgt[(k*4+rv)*64 + s] ; diagonal s==r -> 0
        int k = tid >> 8, rv = (tid >> 6) & 3, s = tid & 63;
        int r = r0 + rv;
        float w = 0.0f;
        if (s != r) {
            int j = s - (s > r ? 1 : 0);
            w = edges[((size_t)b * EE + r * 63 + j) * KK + k];
        }
        smWgt[tid] = w;
    }

    const int lane = tid & 63;
    const int wn   = tid >> 6;    // 8 waves: (rp = wn>>2 receiver-pair, cq = wn&3 col-quarter)
    const int rp   = wn >> 2;
    const int cq   = wn & 3;
    const int ln15 = lane & 15;
    const int lg   = lane >> 4;   // 0..3

    // swizzled u read offsets: byte = s*512 + ((kc*64 + lg*16) ^ ((s&7)<<4)),
    // s = (mi&3)*16 + ln15 -> s&7 = ln15&7 (per-lane constant).
    const int xm45 = (ln15 & 3) << 4;
    const int xm6  = (ln15 & 4) << 4;
    int uoff[8];
    #pragma unroll
    for (int mi = 0; mi < 8; ++mi) {
        int s = (mi & 3) * 16 + ln15;
        uoff[mi] = s * 512 + ((lg * 16) ^ xm45);
    }

    float rsum[2][4];             // [rl][ni], accumulated across k
    #pragma unroll
    for (int rl = 0; rl < 2; ++rl)
        #pragma unroll
        for (int ni = 0; ni < 4; ++ni) rsum[rl][ni] = 0.0f;

    __syncthreads();              // smY/smWgt ready

    // ---- prologue: build k=0 into buf0 ----
    build_uk(smem, 0, 0, tid, W1g, smY);
    build_vbh(smVBH, 0, 0, tid, r0, W1g, b1g, smY);
    __syncthreads();              // u0/vbh0 ready

    // ---- pipelined steady state: build k=1 (VALU) interleaves with GEMM k=0 (MFMA) ----
    build_uk(smem, 1, 1, tid, W1g, smY);
    build_vbh(smVBH, 1, 1, tid, r0, W1g, b1g, smY);
    gemm_k(smem, 0, 0, W2F, b2g, smWgt, lane, rp, cq, ln15, lg, uoff, xm6, rsum);
    __syncthreads();              // u1/vbh1 ready (and all waves done with buf0)

    gemm_k(smem, 1, 1, W2F, b2g, smWgt, lane, rp, cq, ln15, lg, uoff, xm6, rsum);

    // ---- cross-lane reduce + direct global agg write (unique (row,o) writer) ----
    #pragma unroll
    for (int rl = 0; rl < 2; ++rl)
        #pragma unroll
        for (int ni = 0; ni < 4; ++ni) {
            rsum[rl][ni] += __shfl_xor(rsum[rl][ni], 16, 64);
            rsum[rl][ni] += __shfl_xor(rsum[rl][ni], 32, 64);
        }
    if (lane < 16) {
        #pragma unroll
        for (int rl = 0; rl < 2; ++rl)
            #pragma unroll
            for (int ni = 0; ni < 4; ++ni) {
                int o = cq * 64 + ni * 16 + ln15;
                aggg[(size_t)(b * NN + r0 + rp * 2 + rl) * 256 + o] = rsum[rl][ni];
            }
    }
}

// Node MLP (f32-exact) + RK4 tail. Block = 4 rows; 512 blocks.
// v5: hb-loops unroll 2 so next iteration's Wo loads hoist above the FMA chain
// (mlp is load-latency-bound: VALUBusy ~4%).
__global__ __launch_bounds__(256, 4)
void mlp_kernel(int stage, int step,
    const float* __restrict__ Wo1, const float* __restrict__ bo1,
    const float* __restrict__ Wo2, const float* __restrict__ bo2,
    const float* __restrict__ Wo3, const float* __restrict__ bo3,
    const float* __restrict__ ts,  const void* __restrict__ scp,
    const float* __restrict__ xcur, const float* __restrict__ kprev,
    const float* __restrict__ aggg,
    float* __restrict__ kout,
    const float* __restrict__ k1b, const float* __restrict__ k2b,
    const float* __restrict__ k3b,
    float* __restrict__ xnext, float* __restrict__ outp)
{
    __shared__ float smAug[4][264];    // 264 -> 16B-aligned rows
    __shared__ float smP1[4][256];
    __shared__ float smP2[4][256];

    const int tid  = threadIdx.x;
    const int row0 = blockIdx.x * 4;

    const float dt = load_dt(ts, scp, step);
    const float cc = (stage == 0) ? 0.0f : ((stage == 3) ? 1.0f : 0.5f);

    // ---- stage aug = [y(4) | agg(256)] per row ----
    for (int u = tid; u < 1040; u += 256) {
        int rr = u / 260, h = u - rr * 260;
        int row = row0 + rr;
        float v;
        if (h < 4) {
            int gi = row * 4 + h;
            v = xcur[gi];
            if (stage != 0) v += cc * dt * kprev[gi];
            v = scrub(v);
        } else {
            v = aggg[(size_t)row * 256 + (h - 4)];
        }
        smAug[rr][h] = v;
    }
    __syncthreads();

    // ---- L1: 260 -> 256, relu ----
    {
        int c = tid;
        float a[4];
        float b0 = bo1[c];
        #pragma unroll
        for (int rr = 0; rr < 4; ++rr) a[rr] = b0;
        #pragma unroll 2
        for (int hb = 0; hb < 256; hb += 8) {
            float w[8];
            #pragma unroll
            for (int j = 0; j < 8; ++j) w[j] = Wo1[(size_t)(hb + j) * 256 + c];
            f32x4v xlo[4], xhi[4];
            #pragma unroll
            for (int rr = 0; rr < 4; ++rr) {
                xlo[rr] = *(const f32x4v*)(&smAug[rr][hb]);
                xhi[rr] = *(const f32x4v*)(&smAug[rr][hb + 4]);
            }
            #pragma unroll
            for (int jj = 0; jj < 4; ++jj)
                #pragma unroll
                for (int rr = 0; rr < 4; ++rr) {
                    a[rr] += xlo[rr][jj] * w[jj];
                    a[rr] += xhi[rr][jj] * w[4 + jj];
                }
        }
        #pragma unroll
        for (int j = 0; j < 4; ++j) {          // tail h = 256..259
            float wv = Wo1[(size_t)(256 + j) * 256 + c];
            #pragma unroll
            for (int rr = 0; rr < 4; ++rr)
                a[rr] += smAug[rr][256 + j] * wv;
        }
        #pragma unroll
        for (int rr = 0; rr < 4; ++rr)
            smP1[rr][c] = fmaxf(a[rr], 0.0f);
    }
    __syncthreads();
    // ---- L2: 256 -> 256, relu ----
    {
        int c = tid;
        float a[4];
        float b0 = bo2[c];
        #pragma unroll
        for (int rr = 0; rr < 4; ++rr) a[rr] = b0;
        #pragma unroll 2
        for (int hb = 0; hb < 256; hb += 8) {
            float w[8];
            #pragma unroll
            for (int j = 0; j < 8; ++j) w[j] = Wo2[(size_t)(hb + j) * 256 + c];
            f32x4v xlo[4], xhi[4];
            #pragma unroll
            for (int rr = 0; rr < 4; ++rr) {
                xlo[rr] = *(const f32x4v*)(&smP1[rr][hb]);
                xhi[rr] = *(const f32x4v*)(&smP1[rr][hb + 4]);
            }
            #pragma unroll
            for (int jj = 0; jj < 4; ++jj)
                #pragma unroll
                for (int rr = 0; rr < 4; ++rr) {
                    a[rr] += xlo[rr][jj] * w[jj];
                    a[rr] += xhi[rr][jj] * w[4 + jj];
                }
        }
        #pragma unroll
        for (int rr = 0; rr < 4; ++rr)
            smP2[rr][c] = fmaxf(a[rr], 0.0f);
    }
    __syncthreads();
    // ---- L3 (256 -> 4) + residual + RK4 tail ----
    {
        int rr = tid >> 6, f = (tid >> 4) & 3, hs = tid & 15;
        float part = 0.0f;
        #pragma unroll
        for (int j = 0; j < 16; ++j) {
            int h = hs + j * 16;
            part += smP2[rr][h] * Wo3[h * 4 + f];
        }
        part += __shfl_xor(part, 8, 64);
        part += __shfl_xor(part, 4, 64);
        part += __shfl_xor(part, 2, 64);
        part += __shfl_xor(part, 1, 64);
        if (hs == 0) {
            int row = row0 + rr;
            int gi  = row * 4 + f;
            float y = xcur[gi];
            if (stage != 0) y += cc * dt * kprev[gi];
            y = scrub(y);
            float knew = scrub(y + bo3[f] + part);    // f(y) = y + p
            if (stage < 3) {
                kout[gi] = knew;
            } else {
                float xn = scrub(xcur[gi] + (dt * (1.0f / 6.0f)) *
                           (k1b[gi] + 2.0f * k2b[gi] + 2.0f * k3b[gi] + knew));
                xnext[gi] = xn;
                // out layout (B, N, NSTEP, F): row = b*64+n
                outp[(size_t)row * NSTEP * FF + step * FF + f] = xn;
            }
        }
    }
}

// Pre-swizzle W2 -> fragment-major W2F (verified): chunk (k,ot,kc) is
// 1 KiB; lane l holds B[o = ot*16 + (l&15)][h = kc*32 + (l>>4)*8 + e]
__global__ void swizzle_w2(const float* __restrict__ W2, _Float16* __restrict__ W2F)
{
    int idx = blockIdx.x * 256 + threadIdx.x;       // 0 .. 131071
    int k   = idx >> 16;
    int rem = idx & 65535;
    int ch  = rem >> 9;
    int pos = rem & 511;
    int ot  = ch >> 3, kc = ch & 7;
    int l   = pos >> 3, e = pos & 7;
    int o   = ot * 16 + (l & 15);
    int h   = kc * 32 + (l >> 4) * 8 + e;
    W2F[idx] = (_Float16)W2[(size_t)(k * 256 + h) * 256 + o];
}

__global__ void init_x(const float* __restrict__ inp, float* __restrict__ x0)
{
    int i = blockIdx.x * 256 + threadIdx.x;   // i = (b*64+n)*4+f
    if (i < BB * NN * FF) {
        int f = i & 3, bn = i >> 2;
        x0[i] = scrub(inp[(size_t)(bn * TT) * FF + f]);   // inputs[b][n][0][f]
    }
}

static int find_input(const int* in_sizes, int n_in, int want, unsigned char* used, int dflt) {
    if (dflt >= 0 && dflt < n_in && in_sizes[dflt] == want && !used[dflt]) { used[dflt] = 1; return dflt; }
    for (int i = 0; i < n_in; ++i)
        if (!used[i] && in_sizes[i] == want) { used[i] = 1; return i; }
    return dflt;
}

extern "C" void kernel_launch(void* const* d_in, const int* in_sizes, int n_in,
                              void* d_out, int out_size, void* d_ws, size_t ws_size,
                              hipStream_t stream)
{
    unsigned char used[64] = {0};
    int iInp = find_input(in_sizes, n_in, BB*NN*TT*FF, used, 0);
    int iEdg = find_input(in_sizes, n_in, BB*EE*KK,    used, 1);
    (void)find_input(in_sizes, n_in, EE*NN, used, 2);              // rel_rec (unused)
    (void)find_input(in_sizes, n_in, EE*NN, used, 3);              // rel_send (unused)
    int iW1  = find_input(in_sizes, n_in, KK*8*256,  used, 4);
    int ib1  = find_input(in_sizes, n_in, KK*256,    used, 5);
    int iW2  = find_input(in_sizes, n_in, KK*256*256,used, 6);
    int ib2  = find_input(in_sizes, n_in, KK*256,    used, 7);
    int iWo1 = find_input(in_sizes, n_in, 260*256,   used, 8);
    int ibo1 = find_input(in_sizes, n_in, 256,       used, 9);
    int iWo2 = find_input(in_sizes, n_in, 256*256,   used, 10);
    int ibo2 = find_input(in_sizes, n_in, 256,       used, 11);
    int iWo3 = find_input(in_sizes, n_in, 256*4,     used, 12);
    int ibo3 = find_input(in_sizes, n_in, 4,         used, 13);
    int iTs  = find_input(in_sizes, n_in, TT,        used, 14);
    (void)find_input(in_sizes, n_in, 1, used, 15);                 // pred_steps
    int iSc  = find_input(in_sizes, n_in, 1,         used, 16);    // scale

    const float* inputs = (const float*)d_in[iInp];
    const float* edges  = (const float*)d_in[iEdg];
    const float* W1  = (const float*)d_in[iW1];
    const float* b1  = (const float*)d_in[ib1];
    const float* W2  = (const float*)d_in[iW2];
    const float* b2  = (const float*)d_in[ib2];
    const float* Wo1 = (const float*)d_in[iWo1];
    const float* bo1 = (const float*)d_in[ibo1];
    const float* Wo2 = (const float*)d_in[iWo2];
    const float* bo2 = (const float*)d_in[ibo2];
    const float* Wo3 = (const float*)d_in[iWo3];
    const float* bo3 = (const float*)d_in[ibo3];
    const float* ts  = (const float*)d_in[iTs];
    const void*  scp = d_in[iSc];

    char* ws = (char*)d_ws;
    _Float16* W2F = (_Float16*)ws;                     // 262144 B
    float* xA  = (float*)(ws + 262144);
    float* xB  = (float*)(ws + 262144 + 1 * 32768);
    float* k1  = (float*)(ws + 262144 + 2 * 32768);
    float* k2  = (float*)(ws + 262144 + 3 * 32768);
    float* k3  = (float*)(ws + 262144 + 4 * 32768);
    float* agg = (float*)(ws + 262144 + 5 * 32768);    // 2048*256*4 = 2 MiB

    float* outp = (float*)d_out;   // f32 output

    (void)hipFuncSetAttribute((const void*)stage_kernel,
        hipFuncAttributeMaxDynamicSharedMemorySize, SMEM2);

    swizzle_w2<<<dim3(512), dim3(256), 0, stream>>>(W2, W2F);
    init_x<<<dim3(32), dim3(256), 0, stream>>>(inputs, xA);

    float* xc = xA;
    float* xn = xB;
    for (int step = 0; step < NSTEP; ++step) {
        float* kprevs[4] = { xc, k1, k2, k3 };   // kprev per stage (xc unused at s0)
        float* kouts[4]  = { k1, k2, k3, k3 };   // kout per stage (s3 -> tail path)
        for (int s = 0; s < 4; ++s) {
            stage_kernel<<<dim3(512), dim3(512), SMEM2, stream>>>(s, step,
                edges, W1, b1, W2F, b2, ts, scp, xc, kprevs[s], agg);
            mlp_kernel<<<dim3(512), dim3(256), 0, stream>>>(s, step,
                Wo1, bo1, Wo2, bo2, Wo3, bo3, ts, scp, xc, kprevs[s], agg,
                kouts[s], k1, k2, k3, xn, outp);
        }
        float* t = xc; xc = xn; xn = t;
    }
}

// Round 5
// 2161.078 us; speedup vs baseline: 1.7432x; 1.1046x over previous
//
#include <hip/hip_runtime.h>

// Problem constants (fixed by setup_inputs)
#define BB 32
#define NN 64
#define TT 11
#define FF 4
#define KK 2
#define EE 4032      // N*(N-1)
#define NSTEP 10

typedef _Float16 f16x8 __attribute__((ext_vector_type(8)));
typedef float    f32x4v __attribute__((ext_vector_type(4)));

// ---- fused kernel LDS ----
// phase C: u dbuf [2][64][512B XOR-swz] 64K | vbh dbuf [2][8][256]f16 8K |
//          y [64][4]f32 1K | wgt [2][8][64]f32 4K | agg [8][256]f32 8K  => 87040 B
// phase D aliases the u region: aug[8][264]f32 8448 | P1[8][256] 8192 | P2[8][256] 8192
#define OFF_U0   0
#define OFF_VB   65536
#define OFF_Y    73728
#define OFF_WGT  74752
#define OFF_AGG  78848
#define SMEM2    87040
#define OFF_AUG  0
#define OFF_P1   8448
#define OFF_P2   16640

__device__ __forceinline__ float scrub(float v) {
    return fminf(fmaxf(v, -3.0e4f), 3.0e4f);   // inactive when correct (|x| <~ 600)
}

__device__ __forceinline__ float load_dt(const float* ts, const void* scp, int step) {
    float t0 = ts[step], t1 = ts[step + 1];
    int w = ((const int*)scp)[0];
    float scl;
    if (w > 0 && w < 1000000) scl = (float)w;            // int32 (live path)
    else {
        float f = __int_as_float(w);
        scl = (f > 0.5f && f < 1.0e6f) ? f : 10.0f;
    }
    return (t1 - t0) / scl;
}

// u-build (512 thr): u[s][h] = sum_f y_s[f] * W1send[k][f][h], f16, XOR-swizzled rows.
__device__ __forceinline__ void build_uk(char* smem, int buf, int k, int tid,
    const float* __restrict__ W1g, const float* smY)
{
    int hg = tid & 31, sb = tid >> 5;          // sb = 0..15
    const float* w1p = W1g + k * 2048 + hg * 8;
    f32x4v wA[4], wB[4];
    #pragma unroll
    for (int f = 0; f < 4; ++f) {
        wA[f] = *(const f32x4v*)(w1p + f * 256);
        wB[f] = *(const f32x4v*)(w1p + f * 256 + 4);
    }
    const int swz = (hg * 16) ^ ((sb & 7) << 4);   // s&7 == sb&7 (it*16 ≡ 0 mod 8)
    char* ub = smem + OFF_U0 + buf * 32768;
    #pragma unroll
    for (int it = 0; it < 4; ++it) {
        int s = sb + it * 16;
        f32x4v yv = *(const f32x4v*)(smY + s * 4);
        f16x8 uv;
        #pragma unroll
        for (int e = 0; e < 4; ++e) {
            float vA = yv[0]*wA[0][e] + yv[1]*wA[1][e] + yv[2]*wA[2][e] + yv[3]*wA[3][e];
            float vB = yv[0]*wB[0][e] + yv[1]*wB[1][e] + yv[2]*wB[2][e] + yv[3]*wB[3][e];
            uv[e]     = (_Float16)vA;
            uv[e + 4] = (_Float16)vB;
        }
        *(f16x8*)(ub + s * 512 + swz) = uv;
    }
}

// vbh[buf][rv][h] = f16( b1 + sum_f y_recv[f] * W1recv[k][f][h] ), rv = 0..7
__device__ __forceinline__ void build_vbh(_Float16* smVBH, int buf, int k, int tid, int r0,
    const float* __restrict__ W1g, const float* __restrict__ b1g, const float* smY)
{
    #pragma unroll
    for (int it = 0; it < 4; ++it) {
        int i = tid + it * 512;
        int rv = i >> 8, h = i & 255;
        float acch = b1g[k * 256 + h];
        #pragma unroll
        for (int f = 0; f < 4; ++f)
            acch += smY[(r0 + rv) * 4 + f] * W1g[k * 2048 + (4 + f) * 256 + h];
        smVBH[buf * 2048 + i] = (_Float16)acch;
    }
}

// One GEMM pass: 128 rows (pair p: 2 receivers x 64 senders) x 64 cols (quarter q),
// one k. Accumulates relu(acc)*w into smAgg (k==0 stores, k==1 adds).
__device__ __forceinline__ void gemm_pass(char* smem, int buf, int k, int q, int p,
    const _Float16* __restrict__ W2F, const float* __restrict__ b2g,
    const float* smWgt, float* smAgg,
    int lane, int ln15, int lg, const int* uoff, int xm6)
{
    const _Float16* smVBH = (const _Float16*)(smem + OFF_VB);

    float bv[4];
    #pragma unroll
    for (int ni = 0; ni < 4; ++ni)
        bv[ni] = b2g[k * 256 + q * 64 + ni * 16 + ln15];

    f32x4v acc[8][4];         // b2 folded into init
    #pragma unroll
    for (int mi = 0; mi < 8; ++mi)
        #pragma unroll
        for (int ni = 0; ni < 4; ++ni)
            acc[mi][ni] = (f32x4v){bv[ni], bv[ni], bv[ni], bv[ni]};

    const _Float16* bbase = W2F + ((size_t)((k * 16 + q * 4) * 8)) * 512 + lane * 8;
    const char* ubase = smem + OFF_U0 + buf * 32768;
    const char* vbase = (const char*)(smVBH + buf * 2048 + p * 512);  // rows p*2, p*2+1

    #pragma unroll
    for (int kc = 0; kc < 8; ++kc) {
        f16x8 bfr[4];
        #pragma unroll
        for (int ni = 0; ni < 4; ++ni)
            bfr[ni] = *(const f16x8*)(bbase + (size_t)(ni * 8 + kc) * 512);
        f16x8 vbA = *(const f16x8*)(vbase + (kc * 32 + lg * 8) * 2);
        f16x8 vbB = *(const f16x8*)(vbase + (256 + kc * 32 + lg * 8) * 2);
        const int kco = (kc * 64) ^ xm6;
        f16x8 af[8];
        f16x8 z = {};
        #pragma unroll
        for (int mi = 0; mi < 8; ++mi) {
            f16x8 uv = *(const f16x8*)(ubase + uoff[mi] + kco);
            af[mi] = __builtin_elementwise_max(uv + (mi < 4 ? vbA : vbB), z);
        }
        __builtin_amdgcn_s_setprio(1);
        #pragma unroll
        for (int mi = 0; mi < 8; ++mi)
            #pragma unroll
            for (int ni = 0; ni < 4; ++ni)
                acc[mi][ni] = __builtin_amdgcn_mfma_f32_16x16x32_f16(
                    af[mi], bfr[ni], acc[mi][ni], 0, 0, 0);
        __builtin_amdgcn_s_setprio(0);
    }

    // ---- epilogue: relu * edge_w, reduce, accumulate into smAgg ----
    float rsum[2][4];
    #pragma unroll
    for (int rl = 0; rl < 2; ++rl)
        #pragma unroll
        for (int ni = 0; ni < 4; ++ni) rsum[rl][ni] = 0.0f;

    #pragma unroll
    for (int mi = 0; mi < 8; ++mi) {
        int rl = mi >> 2;
        #pragma unroll
        for (int rr = 0; rr < 4; ++rr) {
            // C/D: col = lane&15, row = (lane>>4)*4 + rr  [m89/m91]; sender s = (mi&3)*16 + row
            float w = smWgt[k * 512 + (p * 2 + rl) * 64 + (mi & 3) * 16 + lg * 4 + rr];
            #pragma unroll
            for (int ni = 0; ni < 4; ++ni)
                rsum[rl][ni] += fmaxf(acc[mi][ni][rr], 0.0f) * w;
        }
    }
    #pragma unroll
    for (int rl = 0; rl < 2; ++rl)
        #pragma unroll
        for (int ni = 0; ni < 4; ++ni) {
            rsum[rl][ni] += __shfl_xor(rsum[rl][ni], 16, 64);
            rsum[rl][ni] += __shfl_xor(rsum[rl][ni], 32, 64);
        }
    if (lane < 16) {
        #pragma unroll
        for (int rl = 0; rl < 2; ++rl)
            #pragma unroll
            for (int ni = 0; ni < 4; ++ni) {
                int idx = (p * 2 + rl) * 256 + q * 64 + ni * 16 + ln15;
                float v = rsum[rl][ni];
                if (k) v += smAgg[idx];
                smAgg[idx] = v;
            }
    }
}

// Fused per-stage kernel: edge-GEMM + aggregation + node MLP + RK4 tail.
// Block = (batch, 8 receivers), 512 threads, grid 256 = 1 block/CU (2 waves/SIMD:
// 128 VGPR + 128 AGPR). agg stays in LDS; the node MLP for the block's 8 nodes runs
// as a tail phase (no separate dispatch, no agg round-trip, y reused from smY).
__global__ __launch_bounds__(512, 2)
void stage_kernel(int stage, int step,
    const float* __restrict__ edges, const float* __restrict__ W1g,
    const float* __restrict__ b1g,   const _Float16* __restrict__ W2F,
    const float* __restrict__ b2g,
    const float* __restrict__ Wo1, const float* __restrict__ bo1,
    const float* __restrict__ Wo2, const float* __restrict__ bo2,
    const float* __restrict__ Wo3, const float* __restrict__ bo3,
    const float* __restrict__ ts,  const void* __restrict__ scp,
    const float* __restrict__ xcur, const float* __restrict__ kprev,
    float* __restrict__ kout,
    const float* __restrict__ k1b, const float* __restrict__ k2b,
    const float* __restrict__ k3b,
    float* __restrict__ xnext, float* __restrict__ outp)
{
    extern __shared__ char smem[];
    _Float16* smVBH = (_Float16*)(smem + OFF_VB);
    float*  smY   = (float*)(smem + OFF_Y);
    float*  smWgt = (float*)(smem + OFF_WGT);
    float*  smAgg = (float*)(smem + OFF_AGG);

    const int tid = threadIdx.x;
    const int b   = blockIdx.x >> 3;
    const int rg  = blockIdx.x & 7;
    const int r0  = rg * 8;

    const float dt = load_dt(ts, scp, step);
    const float cc = (stage == 0) ? 0.0f : ((stage == 3) ? 1.0f : 0.5f);

    // ---- P0: y (all 64 nodes), edge weights (sender-major), agg not zeroed (k0 stores) ----
    if (tid < 256) {
        int gi = (b * NN) * FF + tid;           // tid = n*4+f
        float y = xcur[gi];
        if (stage != 0) y += cc * dt * kprev[gi];
        smY[tid] = scrub(y);
    }
    #pragma unroll
    for (int it = 0; it < 2; ++it) {
        // smWgt[k][rv][s] ; diagonal s==r -> 0
        int i = tid + it * 512;
        int k = i >> 9, m = i & 511;
        int rv = m >> 6, s = m & 63;
        int r = r0 + rv;
        float w = 0.0f;
        if (s != r) {
            int j = s - (s > r ? 1 : 0);
            w = edges[((size_t)b * EE + r * 63 + j) * KK + k];
        }
        smWgt[i] = w;
    }

    const int lane = tid & 63;
    const int wn   = tid >> 6;    // 8 waves: p = wn>>1 (receiver pair 0..3), ch = wn&1 (col half)
    const int p    = wn >> 1;
    const int ch   = wn & 1;
    const int ln15 = lane & 15;
    const int lg   = lane >> 4;   // 0..3

    // swizzled u read offsets: byte = s*512 + ((kc*64 + lg*16) ^ ((s&7)<<4)),
    // s = (mi&3)*16 + ln15 -> s&7 = ln15&7 (per-lane constant).
    const int xm45 = (ln15 & 3) << 4;
    const int xm6  = (ln15 & 4) << 4;
    int uoff[8];
    #pragma unroll
    for (int mi = 0; mi < 8; ++mi) {
        int s = (mi & 3) * 16 + ln15;
        uoff[mi] = s * 512 + ((lg * 16) ^ xm45);
    }

    __syncthreads();              // smY/smWgt ready

    // ---- build k=0 into buf0 ----
    build_uk(smem, 0, 0, tid, W1g, smY);
    build_vbh(smVBH, 0, 0, tid, r0, W1g, b1g, smY);
    __syncthreads();              // u0/vbh0 ready

    // ---- build k=1 (VALU) interleaves with GEMM k=0 (MFMA) ----
    build_uk(smem, 1, 1, tid, W1g, smY);
    build_vbh(smVBH, 1, 1, tid, r0, W1g, b1g, smY);
    gemm_pass(smem, 0, 0, ch * 2 + 0, p, W2F, b2g, smWgt, smAgg, lane, ln15, lg, uoff, xm6);
    gemm_pass(smem, 0, 0, ch * 2 + 1, p, W2F, b2g, smWgt, smAgg, lane, ln15, lg, uoff, xm6);
    __syncthreads();              // u1/vbh1 ready
    gemm_pass(smem, 1, 1, ch * 2 + 0, p, W2F, b2g, smWgt, smAgg, lane, ln15, lg, uoff, xm6);
    gemm_pass(smem, 1, 1, ch * 2 + 1, p, W2F, b2g, smWgt, smAgg, lane, ln15, lg, uoff, xm6);
    __syncthreads();              // smAgg complete; u region free for aliasing

    // ======== phase D: node MLP for the block's 8 nodes (rows r0..r0+7) ========
    float* smAug = (float*)(smem + OFF_AUG);   // [8][264]
    float* smP1  = (float*)(smem + OFF_P1);    // [8][256]
    float* smP2  = (float*)(smem + OFF_P2);    // [8][256]

    // ---- aug = [y(4) | agg(256)] per row ----
    for (int u = tid; u < 2080; u += 512) {
        int rr = u / 260, h = u - rr * 260;
        float v;
        if (h < 4) v = smY[(r0 + rr) * 4 + h];
        else       v = smAgg[rr * 256 + (h - 4)];
        smAug[rr * 264 + h] = v;
    }
    __syncthreads();

    const int rh = tid >> 8;      // row half: rows rh*4 .. rh*4+3
    const int c  = tid & 255;

    // ---- L1: 260 -> 256, relu ----
    {
        float a[4];
        float b0 = bo1[c];
        #pragma unroll
        for (int rr = 0; rr < 4; ++rr) a[rr] = b0;
        #pragma unroll 1
        for (int hb = 0; hb < 256; hb += 8) {
            float w[8];
            #pragma unroll
            for (int j = 0; j < 8; ++j) w[j] = Wo1[(size_t)(hb + j) * 256 + c];
            f32x4v xlo[4], xhi[4];
            #pragma unroll
            for (int rr = 0; rr < 4; ++rr) {
                xlo[rr] = *(const f32x4v*)(smAug + (rh * 4 + rr) * 264 + hb);
                xhi[rr] = *(const f32x4v*)(smAug + (rh * 4 + rr) * 264 + hb + 4);
            }
            #pragma unroll
            for (int jj = 0; jj < 4; ++jj)
                #pragma unroll
                for (int rr = 0; rr < 4; ++rr) {
                    a[rr] += xlo[rr][jj] * w[jj];
                    a[rr] += xhi[rr][jj] * w[4 + jj];
                }
        }
        #pragma unroll
        for (int j = 0; j < 4; ++j) {          // tail h = 256..259
            float wv = Wo1[(size_t)(256 + j) * 256 + c];
            #pragma unroll
            for (int rr = 0; rr < 4; ++rr)
                a[rr] += smAug[(rh * 4 + rr) * 264 + 256 + j] * wv;
        }
        #pragma unroll
        for (int rr = 0; rr < 4; ++rr)
            smP1[(rh * 4 + rr) * 256 + c] = fmaxf(a[rr], 0.0f);
    }
    __syncthreads();
    // ---- L2: 256 -> 256, relu ----
    {
        float a[4];
        float b0 = bo2[c];
        #pragma unroll
        for (int rr = 0; rr < 4; ++rr) a[rr] = b0;
        #pragma unroll 1
        for (int hb = 0; hb < 256; hb += 8) {
            float w[8];
            #pragma unroll
            for (int j = 0; j < 8; ++j) w[j] = Wo2[(size_t)(hb + j) * 256 + c];
            f32x4v xlo[4], xhi[4];
            #pragma unroll
            for (int rr = 0; rr < 4; ++rr) {
                xlo[rr] = *(const f32x4v*)(smP1 + (rh * 4 + rr) * 256 + hb);
                xhi[rr] = *(const f32x4v*)(smP1 + (rh * 4 + rr) * 256 + hb + 4);
            }
            #pragma unroll
            for (int jj = 0; jj < 4; ++jj)
                #pragma unroll
                for (int rr = 0; rr < 4; ++rr) {
                    a[rr] += xlo[rr][jj] * w[jj];
                    a[rr] += xhi[rr][jj] * w[4 + jj];
                }
        }
        #pragma unroll
        for (int rr = 0; rr < 4; ++rr)
            smP2[(rh * 4 + rr) * 256 + c] = fmaxf(a[rr], 0.0f);
    }
    __syncthreads();
    // ---- L3 (256 -> 4) + residual + RK4 tail ----
    {
        int rr = tid >> 6, f = (tid >> 4) & 3, hs = tid & 15;   // one wave per row, 8 rows
        float part = 0.0f;
        #pragma unroll
        for (int j = 0; j < 16; ++j) {
            int h = hs + j * 16;
            part += smP2[rr * 256 + h] * Wo3[h * 4 + f];
        }
        part += __shfl_xor(part, 8, 64);
        part += __shfl_xor(part, 4, 64);
        part += __shfl_xor(part, 2, 64);
        part += __shfl_xor(part, 1, 64);
        if (hs == 0) {
            int grow = b * NN + r0 + rr;
            int gi   = grow * 4 + f;
            float y = smY[(r0 + rr) * 4 + f];
            float knew = scrub(y + bo3[f] + part);    // f(y) = y + p
            if (stage < 3) {
                kout[gi] = knew;
            } else {
                float xn = scrub(xcur[gi] + (dt * (1.0f / 6.0f)) *
                           (k1b[gi] + 2.0f * k2b[gi] + 2.0f * k3b[gi] + knew));
                xnext[gi] = xn;
                // out layout (B, N, NSTEP, F): row = b*64+n
                outp[(size_t)grow * NSTEP * FF + step * FF + f] = xn;
            }
        }
    }
}

// Pre-swizzle W2 -> fragment-major W2F (verified): chunk (k,ot,kc) is
// 1 KiB; lane l holds B[o = ot*16 + (l&15)][h = kc*32 + (l>>4)*8 + e]
__global__ void swizzle_w2(const float* __restrict__ W2, _Float16* __restrict__ W2F)
{
    int idx = blockIdx.x * 256 + threadIdx.x;       // 0 .. 131071
    int k   = idx >> 16;
    int rem = idx & 65535;
    int ch  = rem >> 9;
    int pos = rem & 511;
    int ot  = ch >> 3, kc = ch & 7;
    int l   = pos >> 3, e = pos & 7;
    int o   = ot * 16 + (l & 15);
    int h   = kc * 32 + (l >> 4) * 8 + e;
    W2F[idx] = (_Float16)W2[(size_t)(k * 256 + h) * 256 + o];
}

__global__ void init_x(const float* __restrict__ inp, float* __restrict__ x0)
{
    int i = blockIdx.x * 256 + threadIdx.x;   // i = (b*64+n)*4+f
    if (i < BB * NN * FF) {
        int f = i & 3, bn = i >> 2;
        x0[i] = scrub(inp[(size_t)(bn * TT) * FF + f]);   // inputs[b][n][0][f]
    }
}

static int find_input(const int* in_sizes, int n_in, int want, unsigned char* used, int dflt) {
    if (dflt >= 0 && dflt < n_in && in_sizes[dflt] == want && !used[dflt]) { used[dflt] = 1; return dflt; }
    for (int i = 0; i < n_in; ++i)
        if (!used[i] && in_sizes[i] == want) { used[i] = 1; return i; }
    return dflt;
}

extern "C" void kernel_launch(void* const* d_in, const int* in_sizes, int n_in,
                              void* d_out, int out_size, void* d_ws, size_t ws_size,
                              hipStream_t stream)
{
    unsigned char used[64] = {0};
    int iInp = find_input(in_sizes, n_in, BB*NN*TT*FF, used, 0);
    int iEdg = find_input(in_sizes, n_in, BB*EE*KK,    used, 1);
    (void)find_input(in_sizes, n_in, EE*NN, used, 2);              // rel_rec (unused)
    (void)find_input(in_sizes, n_in, EE*NN, used, 3);              // rel_send (unused)
    int iW1  = find_input(in_sizes, n_in, KK*8*256,  used, 4);
    int ib1  = find_input(in_sizes, n_in, KK*256,    used, 5);
    int iW2  = find_input(in_sizes, n_in, KK*256*256,used, 6);
    int ib2  = find_input(in_sizes, n_in, KK*256,    used, 7);
    int iWo1 = find_input(in_sizes, n_in, 260*256,   used, 8);
    int ibo1 = find_input(in_sizes, n_in, 256,       used, 9);
    int iWo2 = find_input(in_sizes, n_in, 256*256,   used, 10);
    int ibo2 = find_input(in_sizes, n_in, 256,       used, 11);
    int iWo3 = find_input(in_sizes, n_in, 256*4,     used, 12);
    int ibo3 = find_input(in_sizes, n_in, 4,         used, 13);
    int iTs  = find_input(in_sizes, n_in, TT,        used, 14);
    (void)find_input(in_sizes, n_in, 1, used, 15);                 // pred_steps
    int iSc  = find_input(in_sizes, n_in, 1,         used, 16);    // scale

    const float* inputs = (const float*)d_in[iInp];
    const float* edges  = (const float*)d_in[iEdg];
    const float* W1  = (const float*)d_in[iW1];
    const float* b1  = (const float*)d_in[ib1];
    const float* W2  = (const float*)d_in[iW2];
    const float* b2  = (const float*)d_in[ib2];
    const float* Wo1 = (const float*)d_in[iWo1];
    const float* bo1 = (const float*)d_in[ibo1];
    const float* Wo2 = (const float*)d_in[iWo2];
    const float* bo2 = (const float*)d_in[ibo2];
    const float* Wo3 = (const float*)d_in[iWo3];
    const float* bo3 = (const float*)d_in[ibo3];
    const float* ts  = (const float*)d_in[iTs];
    const void*  scp = d_in[iSc];

    char* ws = (char*)d_ws;
    _Float16* W2F = (_Float16*)ws;                     // 262144 B
    float* xA  = (float*)(ws + 262144);
    float* xB  = (float*)(ws + 262144 + 1 * 32768);
    float* k1  = (float*)(ws + 262144 + 2 * 32768);
    float* k2  = (float*)(ws + 262144 + 3 * 32768);
    float* k3  = (float*)(ws + 262144 + 4 * 32768);

    float* outp = (float*)d_out;   // f32 output

    (void)hipFuncSetAttribute((const void*)stage_kernel,
        hipFuncAttributeMaxDynamicSharedMemorySize, SMEM2);

    swizzle_w2<<<dim3(512), dim3(256), 0, stream>>>(W2, W2F);
    init_x<<<dim3(32), dim3(256), 0, stream>>>(inputs, xA);

    float* xc = xA;
    float* xn = xB;
    for (int step = 0; step < NSTEP; ++step) {
        float* kprevs[4] = { xc, k1, k2, k3 };   // kprev per stage (xc unused at s0)
        float* kouts[4]  = { k1, k2, k3, k3 };   // kout per stage (s3 -> tail path)
        for (int s = 0; s < 4; ++s) {
            stage_kernel<<<dim3(256), dim3(512), SMEM2, stream>>>(s, step,
                edges, W1, b1, W2F, b2,
                Wo1, bo1, Wo2, bo2, Wo3, bo3, ts, scp, xc, kprevs[s],
                kouts[s], k1, k2, k3, xn, outp);
        }
        float* t = xc; xc = xn; xn = t;
    }
}